// Round 1
// baseline (1005.122 us; speedup 1.0000x reference)
//
#include <hip/hip_runtime.h>
#include <math.h>

#define BB 128
#define PP 34125
#define OO 16
#define CC 21
#define VAR0f 0.1f
#define VAR1f 0.2f
#define THRESHf 0.35f

// ---------------- Phase A: best prior per truth (argmax over P) ----------------
__global__ __launch_bounds__(256) void mb_phaseA(const float* __restrict__ priors,
                                                 const float* __restrict__ targets,
                                                 unsigned* __restrict__ bpi) {
    int b = blockIdx.x, tid = threadIdx.x;
    __shared__ float tr[OO][4];
    __shared__ unsigned long long keys[OO];
    if (tid < OO * 5) {
        int o = tid / 5, c = tid % 5;
        float v = targets[((size_t)b * OO + o) * 5 + c];
        if (c < 4) tr[o][c] = v;
    }
    if (tid < OO) keys[tid] = 0ull;
    __syncthreads();

    unsigned long long best[OO];
#pragma unroll
    for (int o = 0; o < OO; o++) best[o] = 0ull;

    for (int p = tid; p < PP; p += 256) {
        float4 pr = ((const float4*)priors)[p];
        float bx0 = pr.x - pr.z * 0.5f, by0 = pr.y - pr.w * 0.5f;
        float bx1 = pr.x + pr.z * 0.5f, by1 = pr.y + pr.w * 0.5f;
        float area_b = (bx1 - bx0) * (by1 - by0);
#pragma unroll
        for (int o = 0; o < OO; o++) {
            float iw = fminf(tr[o][2], bx1) - fmaxf(tr[o][0], bx0);
            float ih = fminf(tr[o][3], by1) - fmaxf(tr[o][1], by0);
            iw = fmaxf(iw, 0.f); ih = fmaxf(ih, 0.f);
            float inter = iw * ih;
            float area_a = (tr[o][2] - tr[o][0]) * (tr[o][3] - tr[o][1]);
            float iou = inter / (area_a + area_b - inter);
            // iou >= 0 so float bits are monotonic as u32; ~p breaks ties toward smaller p (argmax first-index)
            unsigned long long key =
                ((unsigned long long)__float_as_uint(iou) << 32) |
                (unsigned long long)(0xFFFFFFFFu - (unsigned)p);
            if (key > best[o]) best[o] = key;
        }
    }
#pragma unroll
    for (int o = 0; o < OO; o++) atomicMax(&keys[o], best[o]);
    __syncthreads();
    if (tid < OO) bpi[b * OO + tid] = 0xFFFFFFFFu - (unsigned)(keys[tid] & 0xFFFFFFFFull);
}

// ---------------- Phase C: match + encode + smooth-L1 + CE + mined ----------------
__device__ __forceinline__ float sl1(float d) {
    float a = fabsf(d);
    return (a < 1.f) ? 0.5f * d * d : a - 0.5f;
}

__global__ __launch_bounds__(256) void mb_phaseC(const float* __restrict__ loc_data,
                                                 const float* __restrict__ conf_data,
                                                 const float* __restrict__ priors,
                                                 const float* __restrict__ targets,
                                                 const unsigned* __restrict__ bpi,
                                                 float* __restrict__ mined,
                                                 int* __restrict__ num_pos,
                                                 double* __restrict__ posCE,
                                                 double* __restrict__ loss_l_acc) {
    int b = blockIdx.y, tid = threadIdx.x;
    int p = blockIdx.x * 256 + tid;
    __shared__ float tr[OO][4];
    __shared__ float lab[OO];
    __shared__ unsigned bps[OO];
    if (tid < OO * 5) {
        int o = tid / 5, c = tid % 5;
        float v = targets[((size_t)b * OO + o) * 5 + c];
        if (c < 4) tr[o][c] = v; else lab[o] = v;
    }
    if (tid < OO) bps[tid] = bpi[b * OO + tid];
    __syncthreads();

    float t_lossl = 0.f, t_posce = 0.f;
    int t_pos = 0;

    if (p < PP) {
        float4 pr = ((const float4*)priors)[p];
        float bx0 = pr.x - pr.z * 0.5f, by0 = pr.y - pr.w * 0.5f;
        float bx1 = pr.x + pr.z * 0.5f, by1 = pr.y + pr.w * 0.5f;
        float area_b = (bx1 - bx0) * (by1 - by0);
        float bto = -1.f;
        int bti = 0;
#pragma unroll
        for (int o = 0; o < OO; o++) {
            float iw = fminf(tr[o][2], bx1) - fmaxf(tr[o][0], bx0);
            float ih = fminf(tr[o][3], by1) - fmaxf(tr[o][1], by0);
            iw = fmaxf(iw, 0.f); ih = fmaxf(ih, 0.f);
            float inter = iw * ih;
            float area_a = (tr[o][2] - tr[o][0]) * (tr[o][3] - tr[o][1]);
            float iou = inter / (area_a + area_b - inter);
            if (iou > bto) { bto = iou; bti = o; }   // strict > : argmax first-index
        }
        // override: ascending o, overwrite => numpy scatter last-wins
#pragma unroll
        for (int o = 0; o < OO; o++) {
            if (bps[o] == (unsigned)p) { bto = 2.0f; bti = o; }
        }
        int conf_t = (bto < THRESHf) ? 0 : (int)lab[bti];
        bool pos = conf_t > 0;

        if (pos) {
            float mx0 = tr[bti][0], my0 = tr[bti][1], mx1 = tr[bti][2], my1 = tr[bti][3];
            float gcx = ((mx0 + mx1) * 0.5f - pr.x) / (VAR0f * pr.z);
            float gcy = ((my0 + my1) * 0.5f - pr.y) / (VAR0f * pr.w);
            float gw = logf((mx1 - mx0) / pr.z) / VAR1f;
            float gh = logf((my1 - my0) / pr.w) / VAR1f;
            float4 ld = ((const float4*)loc_data)[(size_t)b * PP + p];
            t_lossl = sl1(ld.x - gcx) + sl1(ld.y - gcy) + sl1(ld.z - gw) + sl1(ld.w - gh);
            t_pos = 1;
        }

        const float* cp = conf_data + ((size_t)b * PP + p) * CC;
        float m = cp[0];
#pragma unroll
        for (int c = 1; c < CC; c++) m = fmaxf(m, cp[c]);
        float s = 0.f;
#pragma unroll
        for (int c = 0; c < CC; c++) s += expf(cp[c] - m);
        float lse = m + logf(s);
        float ce = lse - cp[conf_t];
        if (pos) t_posce = ce;
        mined[(size_t)b * PP + p] = pos ? 0.f : ce;
    }

    // block reductions
    __shared__ float rf[256];
    __shared__ int ri[256];
    rf[tid] = t_lossl; ri[tid] = t_pos;
    __syncthreads();
    for (int s = 128; s > 0; s >>= 1) {
        if (tid < s) { rf[tid] += rf[tid + s]; ri[tid] += ri[tid + s]; }
        __syncthreads();
    }
    float blk_lossl = rf[0]; int blk_pos = ri[0];
    __syncthreads();
    rf[tid] = t_posce;
    __syncthreads();
    for (int s = 128; s > 0; s >>= 1) {
        if (tid < s) rf[tid] += rf[tid + s];
        __syncthreads();
    }
    if (tid == 0) {
        if (blk_lossl != 0.f) atomicAdd(loss_l_acc, (double)blk_lossl);
        if (blk_pos) atomicAdd(&num_pos[b], blk_pos);
        if (rf[0] != 0.f) atomicAdd(&posCE[b], (double)rf[0]);
    }
}

// ---------------- Phase D: per-row radix select top-num_neg + sum ----------------
__global__ __launch_bounds__(256) void mb_phaseD(const float* __restrict__ mined,
                                                 const int* __restrict__ num_pos,
                                                 const double* __restrict__ posCE,
                                                 double* __restrict__ loss_c_acc) {
    int b = blockIdx.x, tid = threadIdx.x;
    __shared__ unsigned hist[256];
    __shared__ unsigned s_prefix;
    __shared__ int s_needed;
    __shared__ double sd[256];

    int np = num_pos[b];
    int num_neg = min(3 * np, PP - 1);
    const float* row = mined + (size_t)b * PP;

    double contrib = posCE[b];

    if (num_neg > 0) {
        unsigned prefix = 0;
        int needed = num_neg;
        for (int pass = 0; pass < 4; pass++) {
            int shift = 24 - 8 * pass;
            for (int i = tid; i < 256; i += 256) hist[i] = 0;
            __syncthreads();
            unsigned hi_mask = (pass == 0) ? 0u : (0xFFFFFFFFu << (shift + 8));
            for (int p = tid; p < PP; p += 256) {
                unsigned x = __float_as_uint(row[p]);
                if ((x & hi_mask) == (prefix & hi_mask))
                    atomicAdd(&hist[(x >> shift) & 0xFFu], 1u);
            }
            __syncthreads();
            if (tid == 0) {
                unsigned cum = 0; int bsel = 0;
                for (int j = 255; j >= 0; j--) {
                    if (cum + hist[j] >= (unsigned)needed) { bsel = j; break; }
                    cum += hist[j];
                }
                s_prefix = prefix | ((unsigned)bsel << shift);
                s_needed = needed - (int)cum;
            }
            __syncthreads();
            prefix = s_prefix;
            needed = s_needed;
            __syncthreads();
        }
        float t = __uint_as_float(prefix);
        double sum_gt = 0.0;
        for (int p = tid; p < PP; p += 256) {
            float x = row[p];
            if (__float_as_uint(x) > prefix) sum_gt += (double)x;
        }
        sd[tid] = sum_gt;
        __syncthreads();
        for (int s = 128; s > 0; s >>= 1) {
            if (tid < s) sd[tid] += sd[tid + s];
            __syncthreads();
        }
        if (tid == 0) contrib += sd[0] + (double)needed * (double)t;
    }
    if (tid == 0) atomicAdd(loss_c_acc, contrib);
}

// ---------------- Phase E: finalize ----------------
__global__ __launch_bounds__(128) void mb_phaseE(const int* __restrict__ num_pos,
                                                 const double* __restrict__ loss_l_acc,
                                                 const double* __restrict__ loss_c_acc,
                                                 float* __restrict__ out) {
    __shared__ int si[128];
    int tid = threadIdx.x;
    si[tid] = (tid < BB) ? num_pos[tid] : 0;
    __syncthreads();
    for (int s = 64; s > 0; s >>= 1) {
        if (tid < s) si[tid] += si[tid + s];
        __syncthreads();
    }
    if (tid == 0) {
        int n = si[0];
        double N = (n > 0) ? (double)n : (double)BB;
        out[0] = (float)(*loss_l_acc / N);
        out[1] = (float)(*loss_c_acc / N);
    }
}

extern "C" void kernel_launch(void* const* d_in, const int* in_sizes, int n_in,
                              void* d_out, int out_size, void* d_ws, size_t ws_size,
                              hipStream_t stream) {
    const float* loc_data  = (const float*)d_in[0];
    const float* conf_data = (const float*)d_in[1];
    const float* priors    = (const float*)d_in[2];
    const float* targets   = (const float*)d_in[3];

    char* ws = (char*)d_ws;
    // layout: [0..8) loss_l, [8..16) loss_c, [64..576) num_pos[B],
    //         [576..1600) posCE[B], [1664..9856) bpi[B*16], [16384..) mined[B*P]
    double*   loss_l  = (double*)(ws + 0);
    double*   loss_c  = (double*)(ws + 8);
    int*      num_pos = (int*)(ws + 64);
    double*   posCE   = (double*)(ws + 576);
    unsigned* bpi     = (unsigned*)(ws + 1664);
    float*    mined   = (float*)(ws + 16384);

    hipMemsetAsync(ws, 0, 16384, stream);

    mb_phaseA<<<BB, 256, 0, stream>>>(priors, targets, bpi);

    dim3 gridC((PP + 255) / 256, BB);
    mb_phaseC<<<gridC, 256, 0, stream>>>(loc_data, conf_data, priors, targets, bpi,
                                         mined, num_pos, posCE, loss_l);

    mb_phaseD<<<BB, 256, 0, stream>>>(mined, num_pos, posCE, loss_c);

    mb_phaseE<<<1, 128, 0, stream>>>(num_pos, loss_l, loss_c, (float*)d_out);
}